// Round 7
// baseline (265.048 us; speedup 1.0000x reference)
//
#include <hip/hip_runtime.h>
#include <math.h>

typedef unsigned short u16;
typedef unsigned int u32;
typedef __attribute__((ext_vector_type(8))) short short8;
typedef __attribute__((ext_vector_type(8))) u16 ushort8_t;
typedef __attribute__((ext_vector_type(4))) u16 ushort4_t;
typedef __attribute__((ext_vector_type(4))) float floatx4;

#define DEV static __device__ __forceinline__

DEV u16 f2b(float f) {
    union { float f; u32 u; } v; v.f = f;
    u32 u = v.u;
    return (u16)((u + 0x7fffu + ((u >> 16) & 1u)) >> 16);
}
DEV float b2f(u16 h) {
    union { u32 u; float f; } v; v.u = ((u32)h) << 16;
    return v.f;
}
DEV float gelu_f(float x) {
    return 0.5f * x * (1.f + erff(x * 0.70710678118654752f));
}

// ---------------- fused weight-cvt + LayerNorm1 ----------------
// blocks 0..3071: f32->bf16 weight conversion. blocks 3072..3615: LN1 rows.
__global__ __launch_bounds__(256) void cvt_ln(
    const float* __restrict__ wq, const float* __restrict__ wk,
    const float* __restrict__ wv, const float* __restrict__ wo,
    const float* __restrict__ w1, const float* __restrict__ w2,
    u16* __restrict__ oq, u16* __restrict__ ok, u16* __restrict__ ov,
    u16* __restrict__ oo, u16* __restrict__ o1, u16* __restrict__ o2,
    const float* __restrict__ hidden, const float* __restrict__ ctx,
    const float* __restrict__ g, const float* __restrict__ bta,
    u16* __restrict__ dst)
{
    if (blockIdx.x < 3072) {
        long i = ((long)blockIdx.x * 256 + threadIdx.x) * 4;
        const float* s; u16* d; long off;
        if (i < 1048576) {
            int seg = (int)(i >> 18);
            off = i & 262143;
            s = seg == 0 ? wq : seg == 1 ? wk : seg == 2 ? wv : wo;
            d = seg == 0 ? oq : seg == 1 ? ok : seg == 2 ? ov : oo;
        } else if (i < 2097152) {
            off = i - 1048576; s = w1; d = o1;
        } else {
            off = i - 2097152; s = w2; d = o2;
        }
        floatx4 v = *(const floatx4*)(s + off);
        ushort4_t r;
        r[0] = f2b(v[0]); r[1] = f2b(v[1]); r[2] = f2b(v[2]); r[3] = f2b(v[3]);
        *(ushort4_t*)(d + off) = r;
        return;
    }
    int wid = threadIdx.x >> 6, lane = threadIdx.x & 63;
    int row = (blockIdx.x - 3072) * 4 + wid;
    if (row >= 2176) return;
    int bi = row / 1088, loc = row % 1088;
    const float* src = (loc < 1024) ? hidden + ((long)(bi * 1024 + loc)) * 512
                                    : ctx + ((long)(bi * 64 + (loc - 1024))) * 512;
    const floatx4* p = (const floatx4*)(src + lane * 8);
    floatx4 a = p[0], b4 = p[1];
    float x[8];
    x[0] = a[0]; x[1] = a[1]; x[2] = a[2]; x[3] = a[3];
    x[4] = b4[0]; x[5] = b4[1]; x[6] = b4[2]; x[7] = b4[3];
    float s = 0.f, sq = 0.f;
#pragma unroll
    for (int j = 0; j < 8; j++) { s += x[j]; sq += x[j] * x[j]; }
#pragma unroll
    for (int m = 1; m < 64; m <<= 1) {
        s += __shfl_xor(s, m, 64);
        sq += __shfl_xor(sq, m, 64);
    }
    float mean = s * (1.f / 512.f);
    float var = sq * (1.f / 512.f) - mean * mean;
    float rstd = rsqrtf(var + 1e-5f);
    const floatx4* gp = (const floatx4*)(g + lane * 8);
    const floatx4* bp = (const floatx4*)(bta + lane * 8);
    floatx4 g0 = gp[0], g1 = gp[1], bb0 = bp[0], bb1 = bp[1];
    float gg[8], bbv[8];
    gg[0] = g0[0]; gg[1] = g0[1]; gg[2] = g0[2]; gg[3] = g0[3];
    gg[4] = g1[0]; gg[5] = g1[1]; gg[6] = g1[2]; gg[7] = g1[3];
    bbv[0] = bb0[0]; bbv[1] = bb0[1]; bbv[2] = bb0[2]; bbv[3] = bb0[3];
    bbv[4] = bb1[0]; bbv[5] = bb1[1]; bbv[6] = bb1[2]; bbv[7] = bb1[3];
    ushort8_t o;
#pragma unroll
    for (int j = 0; j < 8; j++) o[j] = f2b((x[j] - mean) * rstd * gg[j] + bbv[j]);
    *(ushort8_t*)(dst + (long)row * 512 + lane * 8) = o;
}

// ---------------- GEMM: C = act(A @ B^T + bias), 64x128 tile ----------------
// OMODE 1: outb0 bf16 [M][N] (+gelu if ACT).
// OMODE 3: QKV scatter (gn<512 q *rs, <1024 k, else v^T).
// OMODE 4: f32 split-K partial: outf[(z*M+gm)*N+gn].
// OMODE 5: atomicAdd into outf[gm*N+gn] (split-K over z).
template<int ACT, int OMODE>
__global__ __launch_bounds__(256) void gemm_bt(
    const u16* __restrict__ A, const u16* __restrict__ Bw,
    const float* __restrict__ bias0, const float* __restrict__ bias1,
    const float* __restrict__ bias2,
    float* __restrict__ outf, u16* __restrict__ outb0,
    u16* __restrict__ outb1, u16* __restrict__ outb2,
    int M, int N, int K, int ksp)
{
    __shared__ u16 As[64 * 72];
    __shared__ u16 Bs[128 * 72];
    int tid = threadIdx.x;
    int wid = tid >> 6, lane = tid & 63;
    int l16 = lane & 15, lq = lane >> 4;
    int m0 = blockIdx.y * 64, n0 = blockIdx.x * 128;
    int wm = (wid >> 1) * 32, wn = (wid & 1) * 64;
    int srow = tid >> 3;          // 0..31
    int scol = (tid & 7) * 8;     // 0..56
    int kb0 = (OMODE >= 4) ? blockIdx.z * ksp : 0;
    int kend = (OMODE >= 4) ? kb0 + ksp : K;
    floatx4 acc[2][4] = {};
    const u16* Ap = A + (long)(m0 + srow) * K + scol;
    const u16* Bp = Bw + (long)(n0 + srow) * K + scol;
    ushort8_t pa[2], pb[4];
#pragma unroll
    for (int p = 0; p < 2; p++)
        pa[p] = *(const ushort8_t*)(Ap + (long)p * 32 * K + kb0);
#pragma unroll
    for (int p = 0; p < 4; p++)
        pb[p] = *(const ushort8_t*)(Bp + (long)p * 32 * K + kb0);
    for (int k0 = kb0; k0 < kend; k0 += 64) {
#pragma unroll
        for (int p = 0; p < 2; p++)
            *(ushort8_t*)(As + (p * 32 + srow) * 72 + scol) = pa[p];
#pragma unroll
        for (int p = 0; p < 4; p++)
            *(ushort8_t*)(Bs + (p * 32 + srow) * 72 + scol) = pb[p];
        __syncthreads();
        int k1 = k0 + 64;
        if (k1 < kend) {
#pragma unroll
            for (int p = 0; p < 2; p++)
                pa[p] = *(const ushort8_t*)(Ap + (long)p * 32 * K + k1);
#pragma unroll
            for (int p = 0; p < 4; p++)
                pb[p] = *(const ushort8_t*)(Bp + (long)p * 32 * K + k1);
        }
#pragma unroll
        for (int s = 0; s < 2; s++) {
            short8 af[2], bfr[4];
#pragma unroll
            for (int i = 0; i < 2; i++)
                af[i] = *(const short8*)(As + (wm + i * 16 + l16) * 72 + s * 32 + lq * 8);
#pragma unroll
            for (int j = 0; j < 4; j++)
                bfr[j] = *(const short8*)(Bs + (wn + j * 16 + l16) * 72 + s * 32 + lq * 8);
#pragma unroll
            for (int i = 0; i < 2; i++)
#pragma unroll
                for (int j = 0; j < 4; j++)
                    acc[i][j] = __builtin_amdgcn_mfma_f32_16x16x32_bf16(
                        af[i], bfr[j], acc[i][j], 0, 0, 0);
        }
        __syncthreads();
    }
    const float rs = 0.17677669529663687f;  // 1/sqrt(32)
#pragma unroll
    for (int i = 0; i < 2; i++) {
#pragma unroll
        for (int j = 0; j < 4; j++) {
            int gmb = m0 + wm + i * 16 + lq * 4;
            int gn = n0 + wn + j * 16 + l16;
#pragma unroll
            for (int r = 0; r < 4; r++) {
                int gm = gmb + r;
                float v = acc[i][j][r];
                if (OMODE == 1) {
                    v += bias0[gn];
                    if (ACT == 1) v = gelu_f(v);
                    outb0[(long)gm * N + gn] = f2b(v);
                } else if (OMODE == 3) {
                    if (gn < 512) {
                        outb0[(long)gm * 512 + gn] = f2b((v + bias0[gn]) * rs);
                    } else if (gn < 1024) {
                        outb1[(long)gm * 512 + gn - 512] = f2b(v + bias1[gn - 512]);
                    } else {
                        int bi = gm / 1088, tok = gm % 1088;
                        int col = gn - 1024;
                        outb2[((long)((bi * 16 + (col >> 5)) * 32 + (col & 31))) * 1088 + tok]
                            = f2b(v + bias2[col]);
                    }
                } else if (OMODE == 4) {
                    outf[((long)blockIdx.z * M + gm) * N + gn] = v;
                } else {
                    atomicAdd(outf + (long)gm * N + gn, v);
                }
            }
        }
    }
}

// ---------------- fused flash attention (no-max, KV-split x4) ----------------
// grid (16 qtiles, 16 heads, 2b*4split), block 256 (4 waves x 16 query rows)
__global__ __launch_bounds__(256, 6) void attn_kernel(
    const u16* __restrict__ qb, const u16* __restrict__ kb,
    const u16* __restrict__ vt, const float* __restrict__ adj,
    const float* __restrict__ pos, const float* __restrict__ ehc,
    float* __restrict__ o_part, float* __restrict__ l_part)
{
    __shared__ u16 P[4][1152];            // per-wave P tile (16 x 72)
    __shared__ u16 ub[4][1152];           // per-wave bf16 bias tile / pls union
    int b = blockIdx.z >> 2, split = blockIdx.z & 3;
    int h = blockIdx.y, grp = h >> 2;
    int qbase = blockIdx.x * 64;
    int tid = threadIdx.x, wid = tid >> 6, lane = tid & 63;
    int l16 = lane & 15, lq = lane >> 4;
    int kv_begin = (split == 0) ? 0 : 320 + (split - 1) * 256;
    int kv_end = (split == 3) ? 1088 : 320 + split * 256;
    const float inv2ls2 = 10.330578512396695f;  // 1/(2*0.22^2)
    float* pls = (float*)&ub[0][0];
    u16* bt = ub[wid];

    if (grp == 0) {
        for (int t = tid; t < 2048; t += 256) pls[t] = pos[b * 2048 + t];
        __syncthreads();
    }
    int rowbase = qbase + wid * 16;
    int qrow = rowbase + l16;
    short8 qa = *(const short8*)(qb + ((long)(b * 1088 + qrow)) * 512 + h * 32 + lq * 8);
    int irow[4];
#pragma unroll
    for (int r = 0; r < 4; r++) irow[r] = rowbase + lq * 4 + r;
    float ipx[4], ipy[4];
    if (grp == 0) {
#pragma unroll
        for (int r = 0; r < 4; r++) {
            ipx[r] = pls[irow[r] * 2];
            ipy[r] = pls[irow[r] * 2 + 1];
        }
    }

    bool stg = (grp == 1 || grp == 2);
    const float* src = (grp == 1)
        ? adj + ((long)(b * 1024 + rowbase)) * 1024
        : ehc + (((long)(b * 4 + (h - 8))) * 1024 + rowbase) * 1024;
    int row4 = lane >> 4, c16 = (lane & 15) * 4;
    floatx4 pre[4];

    float rsum[4] = {0.f, 0.f, 0.f, 0.f};
    floatx4 o[2] = {};
    floatx4 zacc = {0.f, 0.f, 0.f, 0.f};
    u16* Pw = P[wid];

    if (stg && kv_begin < 1024) {
#pragma unroll
        for (int p = 0; p < 4; p++)
            pre[p] = *(const floatx4*)(src + (long)(p * 4 + row4) * 1024 + kv_begin + c16);
#pragma unroll
        for (int p = 0; p < 4; p++) {
            ushort4_t w4;
#pragma unroll
            for (int e = 0; e < 4; e++) w4[e] = f2b(pre[p][e]);
            *(ushort4_t*)(bt + (p * 4 + row4) * 72 + c16) = w4;
        }
    }

    for (int kv = kv_begin; kv < kv_end; kv += 64) {
        // ---- S = Q K^T (Q pre-scaled by 1/sqrt(hd)) ----
        floatx4 sfr[4];
#pragma unroll
        for (int jf = 0; jf < 4; jf++) {
            int tok = kv + jf * 16 + l16;
            short8 kf = *(const short8*)(kb + ((long)(b * 1088 + tok)) * 512 + h * 32 + lq * 8);
            sfr[jf] = __builtin_amdgcn_mfma_f32_16x16x32_bf16(qa, kf, zacc, 0, 0, 0);
        }
        // prefetch next bias tile (issue early)
        int kvn = kv + 64;
        bool pf = stg && kvn < kv_end && kvn < 1024;
        if (pf) {
#pragma unroll
            for (int p = 0; p < 4; p++)
                pre[p] = *(const floatx4*)(src + (long)(p * 4 + row4) * 1024 + kvn + c16);
        }
        // ---- bias + exp + P ----
#pragma unroll
        for (int jf = 0; jf < 4; jf++) {
            int j = kv + jf * 16 + l16;
            float px = 0.f, py = 0.f;
            if (grp == 0 && j < 1024) { px = pls[2 * j]; py = pls[2 * j + 1]; }
#pragma unroll
            for (int r = 0; r < 4; r++) {
                float bias, scale;
                if (grp == 0) {
                    if (j < 1024) {
                        float dx = ipx[r] - px, dy = ipy[r] - py;
                        float e = __expf(-(dx * dx + dy * dy) * inv2ls2);
                        bias = 2.f * e - 1.f; scale = 0.25f + 0.75f * e;
                    } else { bias = -1.f; scale = 0.25f; }
                } else if (grp == 1) {
                    if (j < 1024) {
                        float a = b2f(bt[(lq * 4 + r) * 72 + jf * 16 + l16]);
                        bias = 2.f * a - 1.f; scale = 0.25f + 0.75f * a;
                    } else { bias = -1.f; scale = 0.25f; }
                } else if (grp == 2) {
                    bias = (j < 1024) ? b2f(bt[(lq * 4 + r) * 72 + jf * 16 + l16]) : 0.f;
                    scale = 1.f;
                } else { bias = 0.f; scale = 1.f; }
                float sv = fminf(sfr[jf][r] + bias, 60.f);
                float p = __expf(sv) * scale;
                rsum[r] += p;
                Pw[(lq * 4 + r) * 72 + jf * 16 + l16] = f2b(p);
            }
        }
        // ---- O += P V ----
#pragma unroll
        for (int s = 0; s < 2; s++) {
            short8 pa = *(const short8*)(Pw + l16 * 72 + s * 32 + lq * 8);
#pragma unroll
            for (int nf = 0; nf < 2; nf++) {
                const u16* vrow = vt + ((long)((b * 16 + h) * 32 + nf * 16 + l16)) * 1088
                                  + kv + s * 32 + lq * 8;
                short8 vf = *(const short8*)vrow;
                o[nf] = __builtin_amdgcn_mfma_f32_16x16x32_bf16(pa, vf, o[nf], 0, 0, 0);
            }
        }
        // write prefetched tile (late)
        if (pf) {
#pragma unroll
            for (int p = 0; p < 4; p++) {
                ushort4_t w4;
#pragma unroll
                for (int e = 0; e < 4; e++) w4[e] = f2b(pre[p][e]);
                *(ushort4_t*)(bt + (p * 4 + row4) * 72 + c16) = w4;
            }
        }
    }
    // deferred row-sum reduce (over l16 within each lq group)
#pragma unroll
    for (int r = 0; r < 4; r++) {
#pragma unroll
        for (int m = 1; m < 16; m <<= 1)
            rsum[r] += __shfl_xor(rsum[r], m, 64);
    }
    long pb = (((long)(split * 2 + b) * 16 + h) * 1024);
#pragma unroll
    for (int nf = 0; nf < 2; nf++)
#pragma unroll
        for (int r = 0; r < 4; r++)
            o_part[(pb + irow[r]) * 32 + nf * 16 + l16] = o[nf][r];
    if (l16 == 0) {
#pragma unroll
        for (int r = 0; r < 4; r++) l_part[pb + irow[r]] = rsum[r];
    }
}

// ---------------- attention combine (4 splits) ----------------
__global__ __launch_bounds__(256) void attn_combine(
    const float* __restrict__ o_part, const float* __restrict__ l_part,
    u16* __restrict__ att)
{
    int idx = blockIdx.x * 256 + threadIdx.x;     // 262144 total
    int c4 = idx & 7;
    int row = (idx >> 3) & 1023;
    int h = (idx >> 13) & 15;
    int b = (idx >> 17) & 1;
    long base = (((long)b * 16 + h) * 1024 + row) * 32 + c4 * 4;
    long lb0 = ((long)b * 16 + h) * 1024 + row;
    floatx4 a = {0.f, 0.f, 0.f, 0.f};
    float lsum = 0.f;
#pragma unroll
    for (int s = 0; s < 4; s++) {
        floatx4 p = *(const floatx4*)(o_part + (long)s * 1048576 + base);
#pragma unroll
        for (int e = 0; e < 4; e++) a[e] += p[e];
        lsum += l_part[(long)s * 32768 + lb0];
    }
    float inv = 1.f / lsum;
    ushort4_t w;
#pragma unroll
    for (int e = 0; e < 4; e++) w[e] = f2b(a[e] * inv);
    *(ushort4_t*)(att + ((long)b * 1024 + row) * 512 + h * 32 + c4 * 4) = w;
}

// ---------------- Wo epilogue: residual + LN2 + out-init(h2+b2) ----------------
__global__ __launch_bounds__(256) void wo_ln2(
    const float* __restrict__ p0, const float* __restrict__ p1,
    const float* __restrict__ bo, const float* __restrict__ hidden,
    const float* __restrict__ g, const float* __restrict__ bta,
    const float* __restrict__ b2, float* __restrict__ out,
    u16* __restrict__ n2)
{
    int wid = threadIdx.x >> 6, lane = threadIdx.x & 63;
    int row = blockIdx.x * 4 + wid;
    long base = (long)row * 512 + lane * 8;
    float x[8];
#pragma unroll
    for (int hp = 0; hp < 2; hp++) {
        floatx4 a = *(const floatx4*)(hidden + base + hp * 4);
        floatx4 q0 = *(const floatx4*)(p0 + base + hp * 4);
        floatx4 q1 = *(const floatx4*)(p1 + base + hp * 4);
        floatx4 bb = *(const floatx4*)(bo + lane * 8 + hp * 4);
#pragma unroll
        for (int e = 0; e < 4; e++) x[hp * 4 + e] = a[e] + q0[e] + q1[e] + bb[e];
    }
    float s = 0.f, sq = 0.f;
#pragma unroll
    for (int j = 0; j < 8; j++) { s += x[j]; sq += x[j] * x[j]; }
#pragma unroll
    for (int m = 1; m < 64; m <<= 1) {
        s += __shfl_xor(s, m, 64);
        sq += __shfl_xor(sq, m, 64);
    }
    float mean = s * (1.f / 512.f);
    float var = sq * (1.f / 512.f) - mean * mean;
    float rstd = rsqrtf(var + 1e-5f);
    // out = h2 + b2 (FF2 atomics add gelu@W2 on top)
#pragma unroll
    for (int hp = 0; hp < 2; hp++) {
        floatx4 bb2 = *(const floatx4*)(b2 + lane * 8 + hp * 4);
        floatx4 w;
#pragma unroll
        for (int e = 0; e < 4; e++) w[e] = x[hp * 4 + e] + bb2[e];
        *(floatx4*)(out + base + hp * 4) = w;
    }
    const floatx4* gp = (const floatx4*)(g + lane * 8);
    const floatx4* bp = (const floatx4*)(bta + lane * 8);
    floatx4 g0 = gp[0], g1 = gp[1], bb0 = bp[0], bb1 = bp[1];
    float gg[8], bbv[8];
    gg[0] = g0[0]; gg[1] = g0[1]; gg[2] = g0[2]; gg[3] = g0[3];
    gg[4] = g1[0]; gg[5] = g1[1]; gg[6] = g1[2]; gg[7] = g1[3];
    bbv[0] = bb0[0]; bbv[1] = bb0[1]; bbv[2] = bb0[2]; bbv[3] = bb0[3];
    bbv[4] = bb1[0]; bbv[5] = bb1[1]; bbv[6] = bb1[2]; bbv[7] = bb1[3];
    ushort8_t ov;
#pragma unroll
    for (int j = 0; j < 8; j++) ov[j] = f2b((x[j] - mean) * rstd * gg[j] + bbv[j]);
    *(ushort8_t*)(n2 + base) = ov;
}

// ---------------- launch ----------------
extern "C" void kernel_launch(void* const* d_in, const int* in_sizes, int n_in,
                              void* d_out, int out_size, void* d_ws, size_t ws_size,
                              hipStream_t stream) {
    const float* hidden = (const float*)d_in[0];
    const float* adjacency = (const float*)d_in[1];
    const float* positions = (const float*)d_in[2];
    const float* context = (const float*)d_in[3];
    const float* ehc = (const float*)d_in[4];
    const float* Wq = (const float*)d_in[5];
    const float* bq = (const float*)d_in[6];
    const float* Wk = (const float*)d_in[7];
    const float* bk = (const float*)d_in[8];
    const float* Wv = (const float*)d_in[9];
    const float* bv = (const float*)d_in[10];
    const float* Wo = (const float*)d_in[11];
    const float* bo = (const float*)d_in[12];
    const float* ln1g = (const float*)d_in[13];
    const float* ln1b = (const float*)d_in[14];
    const float* ln2g = (const float*)d_in[15];
    const float* ln2b = (const float*)d_in[16];
    const float* W1 = (const float*)d_in[17];
    const float* b1 = (const float*)d_in[18];
    const float* W2 = (const float*)d_in[19];
    const float* b2 = (const float*)d_in[20];
    float* out = (float*)d_out;

    char* ws = (char*)d_ws;
    u16* wqkv_b = (u16*)(ws + 0);                 // [1536][512] bf16
    u16* wo_b   = (u16*)(ws + 1572864);
    u16* w1_b   = (u16*)(ws + 2097152);
    u16* w2_b   = (u16*)(ws + 4194304);
    u16* ks_b   = (u16*)(ws + 6291456);           // [2][1088][512]
    u16* q_b    = (u16*)(ws + 8519680);           // [2][1088][512] (pre-scaled)
    u16* k_b    = (u16*)(ws + 10747904);          // [2][1088][512]
    u16* vt_b   = (u16*)(ws + 12976128);          // [2][16][32][1088]
    u16* att_b  = (u16*)(ws + 15204352);          // [2][1024][512]
    u16* n2_b   = (u16*)(ws + 17301504);          // [2048][512]
    u16* g_b    = (u16*)(ws + 19398656);          // [2048][2048]
    float* o_part = (float*)(ws + 27787264);      // [4split][2][16][1024][32] f32
    float* l_part = (float*)(ws + 44564480);      // [4split][2][16][1024] f32
    float* wo_p  = (float*)(ws + 45088768);       // [2][2048][512] f32  (end ~53.5MB)

    cvt_ln<<<3616, 256, 0, stream>>>(Wq, Wk, Wv, Wo, W1, W2,
                                     wqkv_b, wqkv_b + 262144, wqkv_b + 524288,
                                     wo_b, w1_b, w2_b,
                                     hidden, context, ln1g, ln1b, ks_b);
    gemm_bt<0, 3><<<dim3(12, 34), 256, 0, stream>>>(
        ks_b, wqkv_b, bq, bk, bv, nullptr, q_b, k_b, vt_b, 2176, 1536, 512, 0);
    attn_kernel<<<dim3(16, 16, 8), 256, 0, stream>>>(
        q_b, k_b, vt_b, adjacency, positions, ehc, o_part, l_part);
    attn_combine<<<1024, 256, 0, stream>>>(o_part, l_part, att_b);
    gemm_bt<0, 4><<<dim3(4, 32, 2), 256, 0, stream>>>(
        att_b, wo_b, nullptr, nullptr, nullptr, wo_p, nullptr, nullptr, nullptr,
        2048, 512, 512, 256);
    wo_ln2<<<512, 256, 0, stream>>>(wo_p, wo_p + 1048576, bo, hidden,
                                    ln2g, ln2b, b2, out, n2_b);
    gemm_bt<1, 1><<<dim3(16, 32), 256, 0, stream>>>(
        n2_b, w1_b, b1, nullptr, nullptr, nullptr, g_b, nullptr, nullptr,
        2048, 2048, 512, 0);
    gemm_bt<0, 5><<<dim3(4, 32, 4), 256, 0, stream>>>(
        g_b, w2_b, nullptr, nullptr, nullptr, out, nullptr, nullptr, nullptr,
        2048, 512, 2048, 512);
}

// Round 8
// 226.528 us; speedup vs baseline: 1.1700x; 1.1700x over previous
//
#include <hip/hip_runtime.h>
#include <math.h>

typedef unsigned short u16;
typedef unsigned int u32;
typedef __attribute__((ext_vector_type(8))) short short8;
typedef __attribute__((ext_vector_type(8))) u16 ushort8_t;
typedef __attribute__((ext_vector_type(4))) u16 ushort4_t;
typedef __attribute__((ext_vector_type(4))) float floatx4;

#define DEV static __device__ __forceinline__

DEV u16 f2b(float f) {
    union { float f; u32 u; } v; v.f = f;
    u32 u = v.u;
    return (u16)((u + 0x7fffu + ((u >> 16) & 1u)) >> 16);
}
DEV float b2f(u16 h) {
    union { u32 u; float f; } v; v.u = ((u32)h) << 16;
    return v.f;
}
DEV float gelu_f(float x) {
    return 0.5f * x * (1.f + erff(x * 0.70710678118654752f));
}

// ---------------- fused weight-cvt + LayerNorm1 ----------------
// blocks 0..3071: f32->bf16 weight conversion. blocks 3072..3615: LN1 rows.
__global__ __launch_bounds__(256) void cvt_ln(
    const float* __restrict__ wq, const float* __restrict__ wk,
    const float* __restrict__ wv, const float* __restrict__ wo,
    const float* __restrict__ w1, const float* __restrict__ w2,
    u16* __restrict__ oq, u16* __restrict__ ok, u16* __restrict__ ov,
    u16* __restrict__ oo, u16* __restrict__ o1, u16* __restrict__ o2,
    const float* __restrict__ hidden, const float* __restrict__ ctx,
    const float* __restrict__ g, const float* __restrict__ bta,
    u16* __restrict__ dst)
{
    if (blockIdx.x < 3072) {
        long i = ((long)blockIdx.x * 256 + threadIdx.x) * 4;
        const float* s; u16* d; long off;
        if (i < 1048576) {
            int seg = (int)(i >> 18);
            off = i & 262143;
            s = seg == 0 ? wq : seg == 1 ? wk : seg == 2 ? wv : wo;
            d = seg == 0 ? oq : seg == 1 ? ok : seg == 2 ? ov : oo;
        } else if (i < 2097152) {
            off = i - 1048576; s = w1; d = o1;
        } else {
            off = i - 2097152; s = w2; d = o2;
        }
        floatx4 v = *(const floatx4*)(s + off);
        ushort4_t r;
        r[0] = f2b(v[0]); r[1] = f2b(v[1]); r[2] = f2b(v[2]); r[3] = f2b(v[3]);
        *(ushort4_t*)(d + off) = r;
        return;
    }
    int wid = threadIdx.x >> 6, lane = threadIdx.x & 63;
    int row = (blockIdx.x - 3072) * 4 + wid;
    if (row >= 2176) return;
    int bi = row / 1088, loc = row % 1088;
    const float* src = (loc < 1024) ? hidden + ((long)(bi * 1024 + loc)) * 512
                                    : ctx + ((long)(bi * 64 + (loc - 1024))) * 512;
    const floatx4* p = (const floatx4*)(src + lane * 8);
    floatx4 a = p[0], b4 = p[1];
    float x[8];
    x[0] = a[0]; x[1] = a[1]; x[2] = a[2]; x[3] = a[3];
    x[4] = b4[0]; x[5] = b4[1]; x[6] = b4[2]; x[7] = b4[3];
    float s = 0.f, sq = 0.f;
#pragma unroll
    for (int j = 0; j < 8; j++) { s += x[j]; sq += x[j] * x[j]; }
#pragma unroll
    for (int m = 1; m < 64; m <<= 1) {
        s += __shfl_xor(s, m, 64);
        sq += __shfl_xor(sq, m, 64);
    }
    float mean = s * (1.f / 512.f);
    float var = sq * (1.f / 512.f) - mean * mean;
    float rstd = rsqrtf(var + 1e-5f);
    const floatx4* gp = (const floatx4*)(g + lane * 8);
    const floatx4* bp = (const floatx4*)(bta + lane * 8);
    floatx4 g0 = gp[0], g1 = gp[1], bb0 = bp[0], bb1 = bp[1];
    float gg[8], bbv[8];
    gg[0] = g0[0]; gg[1] = g0[1]; gg[2] = g0[2]; gg[3] = g0[3];
    gg[4] = g1[0]; gg[5] = g1[1]; gg[6] = g1[2]; gg[7] = g1[3];
    bbv[0] = bb0[0]; bbv[1] = bb0[1]; bbv[2] = bb0[2]; bbv[3] = bb0[3];
    bbv[4] = bb1[0]; bbv[5] = bb1[1]; bbv[6] = bb1[2]; bbv[7] = bb1[3];
    ushort8_t o;
#pragma unroll
    for (int j = 0; j < 8; j++) o[j] = f2b((x[j] - mean) * rstd * gg[j] + bbv[j]);
    *(ushort8_t*)(dst + (long)row * 512 + lane * 8) = o;
}

// ---------------- GEMM: C = act(A @ B^T + bias), 64x128 tile ----------------
// OMODE 1: outb0 bf16 [M][N] (+gelu if ACT).
// OMODE 3: QKV scatter (gn<512 q *rs, <1024 k, else v^T).
// OMODE 4: f32 split-K partial: outf[(z*M+gm)*N+gn].
// OMODE 5: atomicAdd into outf[gm*N+gn] (split-K over z).
template<int ACT, int OMODE>
__global__ __launch_bounds__(256) void gemm_bt(
    const u16* __restrict__ A, const u16* __restrict__ Bw,
    const float* __restrict__ bias0, const float* __restrict__ bias1,
    const float* __restrict__ bias2,
    float* __restrict__ outf, u16* __restrict__ outb0,
    u16* __restrict__ outb1, u16* __restrict__ outb2,
    int M, int N, int K, int ksp)
{
    __shared__ u16 As[64 * 72];
    __shared__ u16 Bs[128 * 72];
    int tid = threadIdx.x;
    int wid = tid >> 6, lane = tid & 63;
    int l16 = lane & 15, lq = lane >> 4;
    int m0 = blockIdx.y * 64, n0 = blockIdx.x * 128;
    int wm = (wid >> 1) * 32, wn = (wid & 1) * 64;
    int srow = tid >> 3;          // 0..31
    int scol = (tid & 7) * 8;     // 0..56
    int kb0 = (OMODE >= 4) ? blockIdx.z * ksp : 0;
    int kend = (OMODE >= 4) ? kb0 + ksp : K;
    floatx4 acc[2][4] = {};
    const u16* Ap = A + (long)(m0 + srow) * K + scol;
    const u16* Bp = Bw + (long)(n0 + srow) * K + scol;
    ushort8_t pa[2], pb[4];
#pragma unroll
    for (int p = 0; p < 2; p++)
        pa[p] = *(const ushort8_t*)(Ap + (long)p * 32 * K + kb0);
#pragma unroll
    for (int p = 0; p < 4; p++)
        pb[p] = *(const ushort8_t*)(Bp + (long)p * 32 * K + kb0);
    for (int k0 = kb0; k0 < kend; k0 += 64) {
#pragma unroll
        for (int p = 0; p < 2; p++)
            *(ushort8_t*)(As + (p * 32 + srow) * 72 + scol) = pa[p];
#pragma unroll
        for (int p = 0; p < 4; p++)
            *(ushort8_t*)(Bs + (p * 32 + srow) * 72 + scol) = pb[p];
        __syncthreads();
        int k1 = k0 + 64;
        if (k1 < kend) {
#pragma unroll
            for (int p = 0; p < 2; p++)
                pa[p] = *(const ushort8_t*)(Ap + (long)p * 32 * K + k1);
#pragma unroll
            for (int p = 0; p < 4; p++)
                pb[p] = *(const ushort8_t*)(Bp + (long)p * 32 * K + k1);
        }
#pragma unroll
        for (int s = 0; s < 2; s++) {
            short8 af[2], bfr[4];
#pragma unroll
            for (int i = 0; i < 2; i++)
                af[i] = *(const short8*)(As + (wm + i * 16 + l16) * 72 + s * 32 + lq * 8);
#pragma unroll
            for (int j = 0; j < 4; j++)
                bfr[j] = *(const short8*)(Bs + (wn + j * 16 + l16) * 72 + s * 32 + lq * 8);
#pragma unroll
            for (int i = 0; i < 2; i++)
#pragma unroll
                for (int j = 0; j < 4; j++)
                    acc[i][j] = __builtin_amdgcn_mfma_f32_16x16x32_bf16(
                        af[i], bfr[j], acc[i][j], 0, 0, 0);
        }
        __syncthreads();
    }
    const float rs = 0.17677669529663687f;  // 1/sqrt(32)
#pragma unroll
    for (int i = 0; i < 2; i++) {
#pragma unroll
        for (int j = 0; j < 4; j++) {
            int gmb = m0 + wm + i * 16 + lq * 4;
            int gn = n0 + wn + j * 16 + l16;
#pragma unroll
            for (int r = 0; r < 4; r++) {
                int gm = gmb + r;
                float v = acc[i][j][r];
                if (OMODE == 1) {
                    v += bias0[gn];
                    if (ACT == 1) v = gelu_f(v);
                    outb0[(long)gm * N + gn] = f2b(v);
                } else if (OMODE == 3) {
                    if (gn < 512) {
                        outb0[(long)gm * 512 + gn] = f2b((v + bias0[gn]) * rs);
                    } else if (gn < 1024) {
                        outb1[(long)gm * 512 + gn - 512] = f2b(v + bias1[gn - 512]);
                    } else {
                        int bi = gm / 1088, tok = gm % 1088;
                        int col = gn - 1024;
                        outb2[((long)((bi * 16 + (col >> 5)) * 32 + (col & 31))) * 1088 + tok]
                            = f2b(v + bias2[col]);
                    }
                } else if (OMODE == 4) {
                    outf[((long)blockIdx.z * M + gm) * N + gn] = v;
                } else {
                    atomicAdd(outf + (long)gm * N + gn, v);
                }
            }
        }
    }
}

// ---------------- fused flash attention (no-max, KV-split x4) ----------------
// grid (16 qtiles, 16 heads, 2b*4split), block 256 (4 waves x 16 query rows)
// NOTE: no min-waves clamp — R7 showed __launch_bounds__(256,6) forced VGPR=40
// and spilled to scratch (+26MB TCC WRITE anomaly, 2x duration).
__global__ __launch_bounds__(256) void attn_kernel(
    const u16* __restrict__ qb, const u16* __restrict__ kb,
    const u16* __restrict__ vt, const float* __restrict__ adj,
    const float* __restrict__ pos, const float* __restrict__ ehc,
    float* __restrict__ o_part, float* __restrict__ l_part)
{
    __shared__ u16 P[4][1152];            // per-wave P tile (16 x 72)
    __shared__ u16 ub[4][1152];           // per-wave bf16 bias tile / pls union
    int b = blockIdx.z >> 2, split = blockIdx.z & 3;
    int h = blockIdx.y, grp = h >> 2;
    int qbase = blockIdx.x * 64;
    int tid = threadIdx.x, wid = tid >> 6, lane = tid & 63;
    int l16 = lane & 15, lq = lane >> 4;
    int kv_begin = (split == 0) ? 0 : 320 + (split - 1) * 256;
    int kv_end = (split == 3) ? 1088 : 320 + split * 256;
    const float inv2ls2 = 10.330578512396695f;  // 1/(2*0.22^2)
    float* pls = (float*)&ub[0][0];
    u16* bt = ub[wid];

    if (grp == 0) {
        for (int t = tid; t < 2048; t += 256) pls[t] = pos[b * 2048 + t];
        __syncthreads();
    }
    int rowbase = qbase + wid * 16;
    int qrow = rowbase + l16;
    short8 qa = *(const short8*)(qb + ((long)(b * 1088 + qrow)) * 512 + h * 32 + lq * 8);
    int irow[4];
#pragma unroll
    for (int r = 0; r < 4; r++) irow[r] = rowbase + lq * 4 + r;
    float ipx[4], ipy[4];
    if (grp == 0) {
#pragma unroll
        for (int r = 0; r < 4; r++) {
            ipx[r] = pls[irow[r] * 2];
            ipy[r] = pls[irow[r] * 2 + 1];
        }
    }

    bool stg = (grp == 1 || grp == 2);
    const float* src = (grp == 1)
        ? adj + ((long)(b * 1024 + rowbase)) * 1024
        : ehc + (((long)(b * 4 + (h - 8))) * 1024 + rowbase) * 1024;
    int row4 = lane >> 4, c16 = (lane & 15) * 4;
    floatx4 pre[4];

    float rsum[4] = {0.f, 0.f, 0.f, 0.f};
    floatx4 o[2] = {};
    floatx4 zacc = {0.f, 0.f, 0.f, 0.f};
    u16* Pw = P[wid];

    if (stg && kv_begin < 1024) {
#pragma unroll
        for (int p = 0; p < 4; p++)
            pre[p] = *(const floatx4*)(src + (long)(p * 4 + row4) * 1024 + kv_begin + c16);
#pragma unroll
        for (int p = 0; p < 4; p++) {
            ushort4_t w4;
#pragma unroll
            for (int e = 0; e < 4; e++) w4[e] = f2b(pre[p][e]);
            *(ushort4_t*)(bt + (p * 4 + row4) * 72 + c16) = w4;
        }
    }

    for (int kv = kv_begin; kv < kv_end; kv += 64) {
        // ---- S = Q K^T (Q pre-scaled by 1/sqrt(hd)) ----
        floatx4 sfr[4];
#pragma unroll
        for (int jf = 0; jf < 4; jf++) {
            int tok = kv + jf * 16 + l16;
            short8 kf = *(const short8*)(kb + ((long)(b * 1088 + tok)) * 512 + h * 32 + lq * 8);
            sfr[jf] = __builtin_amdgcn_mfma_f32_16x16x32_bf16(qa, kf, zacc, 0, 0, 0);
        }
        // prefetch next bias tile (issue early)
        int kvn = kv + 64;
        bool pf = stg && kvn < kv_end && kvn < 1024;
        if (pf) {
#pragma unroll
            for (int p = 0; p < 4; p++)
                pre[p] = *(const floatx4*)(src + (long)(p * 4 + row4) * 1024 + kvn + c16);
        }
        // ---- bias + exp + P ----
#pragma unroll
        for (int jf = 0; jf < 4; jf++) {
            int j = kv + jf * 16 + l16;
            float px = 0.f, py = 0.f;
            if (grp == 0 && j < 1024) { px = pls[2 * j]; py = pls[2 * j + 1]; }
#pragma unroll
            for (int r = 0; r < 4; r++) {
                float bias, scale;
                if (grp == 0) {
                    if (j < 1024) {
                        float dx = ipx[r] - px, dy = ipy[r] - py;
                        float e = __expf(-(dx * dx + dy * dy) * inv2ls2);
                        bias = 2.f * e - 1.f; scale = 0.25f + 0.75f * e;
                    } else { bias = -1.f; scale = 0.25f; }
                } else if (grp == 1) {
                    if (j < 1024) {
                        float a = b2f(bt[(lq * 4 + r) * 72 + jf * 16 + l16]);
                        bias = 2.f * a - 1.f; scale = 0.25f + 0.75f * a;
                    } else { bias = -1.f; scale = 0.25f; }
                } else if (grp == 2) {
                    bias = (j < 1024) ? b2f(bt[(lq * 4 + r) * 72 + jf * 16 + l16]) : 0.f;
                    scale = 1.f;
                } else { bias = 0.f; scale = 1.f; }
                float sv = fminf(sfr[jf][r] + bias, 60.f);
                float p = __expf(sv) * scale;
                rsum[r] += p;
                Pw[(lq * 4 + r) * 72 + jf * 16 + l16] = f2b(p);
            }
        }
        // ---- O += P V ----
#pragma unroll
        for (int s = 0; s < 2; s++) {
            short8 pa = *(const short8*)(Pw + l16 * 72 + s * 32 + lq * 8);
#pragma unroll
            for (int nf = 0; nf < 2; nf++) {
                const u16* vrow = vt + ((long)((b * 16 + h) * 32 + nf * 16 + l16)) * 1088
                                  + kv + s * 32 + lq * 8;
                short8 vf = *(const short8*)vrow;
                o[nf] = __builtin_amdgcn_mfma_f32_16x16x32_bf16(pa, vf, o[nf], 0, 0, 0);
            }
        }
        // write prefetched tile (late)
        if (pf) {
#pragma unroll
            for (int p = 0; p < 4; p++) {
                ushort4_t w4;
#pragma unroll
                for (int e = 0; e < 4; e++) w4[e] = f2b(pre[p][e]);
                *(ushort4_t*)(bt + (p * 4 + row4) * 72 + c16) = w4;
            }
        }
    }
    // deferred row-sum reduce (over l16 within each lq group)
#pragma unroll
    for (int r = 0; r < 4; r++) {
#pragma unroll
        for (int m = 1; m < 16; m <<= 1)
            rsum[r] += __shfl_xor(rsum[r], m, 64);
    }
    long pb = (((long)(split * 2 + b) * 16 + h) * 1024);
#pragma unroll
    for (int nf = 0; nf < 2; nf++)
#pragma unroll
        for (int r = 0; r < 4; r++)
            o_part[(pb + irow[r]) * 32 + nf * 16 + l16] = o[nf][r];
    if (l16 == 0) {
#pragma unroll
        for (int r = 0; r < 4; r++) l_part[pb + irow[r]] = rsum[r];
    }
}

// ---------------- attention combine (4 splits) ----------------
__global__ __launch_bounds__(256) void attn_combine(
    const float* __restrict__ o_part, const float* __restrict__ l_part,
    u16* __restrict__ att)
{
    int idx = blockIdx.x * 256 + threadIdx.x;     // 262144 total
    int c4 = idx & 7;
    int row = (idx >> 3) & 1023;
    int h = (idx >> 13) & 15;
    int b = (idx >> 17) & 1;
    long base = (((long)b * 16 + h) * 1024 + row) * 32 + c4 * 4;
    long lb0 = ((long)b * 16 + h) * 1024 + row;
    floatx4 a = {0.f, 0.f, 0.f, 0.f};
    float lsum = 0.f;
#pragma unroll
    for (int s = 0; s < 4; s++) {
        floatx4 p = *(const floatx4*)(o_part + (long)s * 1048576 + base);
#pragma unroll
        for (int e = 0; e < 4; e++) a[e] += p[e];
        lsum += l_part[(long)s * 32768 + lb0];
    }
    float inv = 1.f / lsum;
    ushort4_t w;
#pragma unroll
    for (int e = 0; e < 4; e++) w[e] = f2b(a[e] * inv);
    *(ushort4_t*)(att + ((long)b * 1024 + row) * 512 + h * 32 + c4 * 4) = w;
}

// ---------------- Wo epilogue: residual + LN2 + out-init(h2+b2) ----------------
__global__ __launch_bounds__(256) void wo_ln2(
    const float* __restrict__ p0, const float* __restrict__ p1,
    const float* __restrict__ bo, const float* __restrict__ hidden,
    const float* __restrict__ g, const float* __restrict__ bta,
    const float* __restrict__ b2, float* __restrict__ out,
    u16* __restrict__ n2)
{
    int wid = threadIdx.x >> 6, lane = threadIdx.x & 63;
    int row = blockIdx.x * 4 + wid;
    long base = (long)row * 512 + lane * 8;
    float x[8];
#pragma unroll
    for (int hp = 0; hp < 2; hp++) {
        floatx4 a = *(const floatx4*)(hidden + base + hp * 4);
        floatx4 q0 = *(const floatx4*)(p0 + base + hp * 4);
        floatx4 q1 = *(const floatx4*)(p1 + base + hp * 4);
        floatx4 bb = *(const floatx4*)(bo + lane * 8 + hp * 4);
#pragma unroll
        for (int e = 0; e < 4; e++) x[hp * 4 + e] = a[e] + q0[e] + q1[e] + bb[e];
    }
    float s = 0.f, sq = 0.f;
#pragma unroll
    for (int j = 0; j < 8; j++) { s += x[j]; sq += x[j] * x[j]; }
#pragma unroll
    for (int m = 1; m < 64; m <<= 1) {
        s += __shfl_xor(s, m, 64);
        sq += __shfl_xor(sq, m, 64);
    }
    float mean = s * (1.f / 512.f);
    float var = sq * (1.f / 512.f) - mean * mean;
    float rstd = rsqrtf(var + 1e-5f);
    // out = h2 + b2 (FF2 atomics add gelu@W2 on top)
#pragma unroll
    for (int hp = 0; hp < 2; hp++) {
        floatx4 bb2 = *(const floatx4*)(b2 + lane * 8 + hp * 4);
        floatx4 w;
#pragma unroll
        for (int e = 0; e < 4; e++) w[e] = x[hp * 4 + e] + bb2[e];
        *(floatx4*)(out + base + hp * 4) = w;
    }
    const floatx4* gp = (const floatx4*)(g + lane * 8);
    const floatx4* bp = (const floatx4*)(bta + lane * 8);
    floatx4 g0 = gp[0], g1 = gp[1], bb0 = bp[0], bb1 = bp[1];
    float gg[8], bbv[8];
    gg[0] = g0[0]; gg[1] = g0[1]; gg[2] = g0[2]; gg[3] = g0[3];
    gg[4] = g1[0]; gg[5] = g1[1]; gg[6] = g1[2]; gg[7] = g1[3];
    bbv[0] = bb0[0]; bbv[1] = bb0[1]; bbv[2] = bb0[2]; bbv[3] = bb0[3];
    bbv[4] = bb1[0]; bbv[5] = bb1[1]; bbv[6] = bb1[2]; bbv[7] = bb1[3];
    ushort8_t ov;
#pragma unroll
    for (int j = 0; j < 8; j++) ov[j] = f2b((x[j] - mean) * rstd * gg[j] + bbv[j]);
    *(ushort8_t*)(n2 + base) = ov;
}

// ---------------- launch ----------------
extern "C" void kernel_launch(void* const* d_in, const int* in_sizes, int n_in,
                              void* d_out, int out_size, void* d_ws, size_t ws_size,
                              hipStream_t stream) {
    const float* hidden = (const float*)d_in[0];
    const float* adjacency = (const float*)d_in[1];
    const float* positions = (const float*)d_in[2];
    const float* context = (const float*)d_in[3];
    const float* ehc = (const float*)d_in[4];
    const float* Wq = (const float*)d_in[5];
    const float* bq = (const float*)d_in[6];
    const float* Wk = (const float*)d_in[7];
    const float* bk = (const float*)d_in[8];
    const float* Wv = (const float*)d_in[9];
    const float* bv = (const float*)d_in[10];
    const float* Wo = (const float*)d_in[11];
    const float* bo = (const float*)d_in[12];
    const float* ln1g = (const float*)d_in[13];
    const float* ln1b = (const float*)d_in[14];
    const float* ln2g = (const float*)d_in[15];
    const float* ln2b = (const float*)d_in[16];
    const float* W1 = (const float*)d_in[17];
    const float* b1 = (const float*)d_in[18];
    const float* W2 = (const float*)d_in[19];
    const float* b2 = (const float*)d_in[20];
    float* out = (float*)d_out;

    char* ws = (char*)d_ws;
    u16* wqkv_b = (u16*)(ws + 0);                 // [1536][512] bf16
    u16* wo_b   = (u16*)(ws + 1572864);
    u16* w1_b   = (u16*)(ws + 2097152);
    u16* w2_b   = (u16*)(ws + 4194304);
    u16* ks_b   = (u16*)(ws + 6291456);           // [2][1088][512]
    u16* q_b    = (u16*)(ws + 8519680);           // [2][1088][512] (pre-scaled)
    u16* k_b    = (u16*)(ws + 10747904);          // [2][1088][512]
    u16* vt_b   = (u16*)(ws + 12976128);          // [2][16][32][1088]
    u16* att_b  = (u16*)(ws + 15204352);          // [2][1024][512]
    u16* n2_b   = (u16*)(ws + 17301504);          // [2048][512]
    u16* g_b    = (u16*)(ws + 19398656);          // [2048][2048]
    float* o_part = (float*)(ws + 27787264);      // [4split][2][16][1024][32] f32
    float* l_part = (float*)(ws + 44564480);      // [4split][2][16][1024] f32
    float* wo_p  = (float*)(ws + 45088768);       // [2][2048][512] f32  (end ~53.5MB)

    cvt_ln<<<3616, 256, 0, stream>>>(Wq, Wk, Wv, Wo, W1, W2,
                                     wqkv_b, wqkv_b + 262144, wqkv_b + 524288,
                                     wo_b, w1_b, w2_b,
                                     hidden, context, ln1g, ln1b, ks_b);
    gemm_bt<0, 3><<<dim3(12, 34), 256, 0, stream>>>(
        ks_b, wqkv_b, bq, bk, bv, nullptr, q_b, k_b, vt_b, 2176, 1536, 512, 0);
    attn_kernel<<<dim3(16, 16, 8), 256, 0, stream>>>(
        q_b, k_b, vt_b, adjacency, positions, ehc, o_part, l_part);
    attn_combine<<<1024, 256, 0, stream>>>(o_part, l_part, att_b);
    gemm_bt<0, 4><<<dim3(4, 32, 2), 256, 0, stream>>>(
        att_b, wo_b, nullptr, nullptr, nullptr, wo_p, nullptr, nullptr, nullptr,
        2048, 512, 512, 256);
    wo_ln2<<<512, 256, 0, stream>>>(wo_p, wo_p + 1048576, bo, hidden,
                                    ln2g, ln2b, b2, out, n2_b);
    gemm_bt<1, 1><<<dim3(16, 32), 256, 0, stream>>>(
        n2_b, w1_b, b1, nullptr, nullptr, nullptr, g_b, nullptr, nullptr,
        2048, 2048, 512, 0);
    gemm_bt<0, 5><<<dim3(4, 32, 4), 256, 0, stream>>>(
        g_b, w2_b, nullptr, nullptr, nullptr, out, nullptr, nullptr, nullptr,
        2048, 512, 2048, 512);
}